// Round 13
// baseline (1025.762 us; speedup 1.0000x reference)
//
#include <hip/hip_runtime.h>

#define T_STEPS 512
#define F_IN    64
#define HID     20
#define NCLS    10
#define BATCH   1024

typedef __attribute__((ext_vector_type(8))) short bf16x8;   // MFMA A/B operand
typedef __attribute__((ext_vector_type(4))) float f32x4;    // MFMA C/D operand
typedef __attribute__((ext_vector_type(2))) float f32x2;

__device__ __forceinline__ float rcpf(float x) { return __builtin_amdgcn_rcpf(x); }
__device__ __forceinline__ float bperm(int idxBytes, float v) {
    return __int_as_float(__builtin_amdgcn_ds_bpermute(idxBytes, __float_as_int(v)));
}
__device__ __forceinline__ unsigned short bf16h(float v) {  // fp32 -> bf16 bits, RNE
    unsigned u = __float_as_uint(v);
    return (unsigned short)((u + 0x7fffu + ((u >> 16) & 1u)) >> 16);
}
__device__ __forceinline__ float bf16f(unsigned short h) {  // bf16 bits -> fp32
    return __uint_as_float(((unsigned)h) << 16);
}
// packed fp32 FMA (the 157 TF fp32 path)
__device__ __forceinline__ f32x2 pkfma(f32x2 a, f32x2 b, f32x2 c) {
    f32x2 d;
    asm("v_pk_fma_f32 %0, %1, %2, %3" : "=v"(d) : "v"(a), "v"(b), "v"(c));
    return d;
}
// fp32x8 -> hi/lo bf16x8 planes
__device__ __forceinline__ void mk8(const float4 u, const float4 v, bf16x8& h, bf16x8& g) {
    const float vv[8] = {u.x, u.y, u.z, u.w, v.x, v.y, v.z, v.w};
    #pragma unroll
    for (int i = 0; i < 8; ++i) {
        const unsigned short hh = bf16h(vv[i]);
        h[i] = (short)hh;
        g[i] = (short)bf16h(vv[i] - bf16f(hh));
    }
}

// ---------------- fused kernel: 3 waves/block, 1 batch elem/block ----------------
// wave0: layer0(t) + FC(t-4)   [R9 code, z now from LDS zring]
// wave1: layer1(t-2)           [R9 code verbatim]
// wave2: Z-producer — split-bf16 MFMA of x[b] @ W_ih0^T + b0, 16-step chunks,
//        2 windows ahead, into a 48-row LDS ring (3 windows; no reader aliasing).
// Barrier (lgkm-only) every 2 steps. Grid 1024 x 192 -> 3 waves/SIMD.
extern "C" __global__ __launch_bounds__(192, 3)
void lstm_fused(const float* __restrict__ x,
                const float* __restrict__ W_ih0, const float* __restrict__ W_hh0,
                const float* __restrict__ b0,
                const float* __restrict__ W_ih1, const float* __restrict__ W_hh1,
                const float* __restrict__ b1,
                const float* __restrict__ W_fc, const float* __restrict__ b_fc,
                float* __restrict__ out)
{
    __shared__ float zring[48 * 80];        // [3 windows x 16 steps][80 gates], 15360 B
    __shared__ float4 ringH0v[4][6];        // [slot][24 floats]
    __shared__ float4 ringH1v[8][6];
    float* ringH0 = (float*)ringH0v;
    float* ringH1 = (float*)ringH1v;

    const int tid = threadIdx.x;
    const int l   = tid & 63;
    const int wid = tid >> 6;               // 0:L0+FC  1:L1  2:Z-producer
    const int b   = blockIdx.x;
    const int g2  = 64 + (l & 15);          // secondary gate = o[4..19]
    const bool isG = (l >= 40 && l < 60);

    const float mnegP = isG ? -2.885390082f : -1.442695041f;
    const float sclP  = isG ? 2.0f : 1.0f;
    const float biaP  = isG ? -1.0f : 0.0f;

    const int idxF  = ((l + 20) & 63) << 2;
    const int idxG  = ((l + 40) & 63) << 2;
    const int idxO  = ((l + 60) & 63) << 2;
    const int idxOB = ((l -  4) & 63) << 2;

    for (int i = tid; i < 96; i += 192)  ringH0[i] = 0.f;
    for (int i = tid; i < 192; i += 192) ringH1[i] = 0.f;

    // ---------------- wave-0 state ----------------
    f32x2 wh0p2[10], wh0s2[10];
    float c0 = 0.f;
    float zpc = 0.f, zsc = 0.f;
    f32x2 facc2 = {0.f, 0.f};
    float4 wfc = make_float4(0.f, 0.f, 0.f, 0.f);
    unsigned wfOff = 0;
    int c4off = 0;
    const char* Wfb = (const char*)W_fc;

    // ---------------- wave-1 state ----------------
    f32x2 wi1p2[10], wi1s2[10], wh1p2[10], wh1s2[10];
    float b1p = 0.f, b1s = 0.f;
    float c1 = 0.f;

    // ---------------- wave-2 state ----------------
    bf16x8 bfr[5][2][2];                    // [n][s][plane] W_ih0 fragments
    float  bb5[5];
    float4 xu0, xv0, xu1, xv1;              // prefetched x for next chunk
    const int ar = l & 15, aq = l >> 4;
    const float* xb = x + (size_t)b * T_STEPS * F_IN;

    // issue the 4 global x loads for chunk c into regs (consumed next window)
    auto loadx = [&](int c) {
        const float* xp = xb + (c * 16 + ar) * F_IN + aq * 8;
        xu0 = *(const float4*)(xp);
        xv0 = *(const float4*)(xp + 4);
        xu1 = *(const float4*)(xp + 32);
        xv1 = *(const float4*)(xp + 36);
    };
    // convert regs -> frags, 30 MFMA, write 16x80 into zring window c%3
    auto zchunk = [&](int c) {
        bf16x8 ah[2], al[2];
        mk8(xu0, xv0, ah[0], al[0]);
        mk8(xu1, xv1, ah[1], al[1]);
        const int rbase = (c % 3) * 16;
        #pragma unroll
        for (int n = 0; n < 5; ++n) {
            f32x4 acc = {bb5[n], bb5[n], bb5[n], bb5[n]};
            #pragma unroll
            for (int s = 0; s < 2; ++s) {
                acc = __builtin_amdgcn_mfma_f32_16x16x32_bf16(ah[s], bfr[n][s][0], acc, 0, 0, 0);
                acc = __builtin_amdgcn_mfma_f32_16x16x32_bf16(ah[s], bfr[n][s][1], acc, 0, 0, 0);
                acc = __builtin_amdgcn_mfma_f32_16x16x32_bf16(al[s], bfr[n][s][0], acc, 0, 0, 0);
            }
            // C/D: col = l&15, row = (l>>4)*4 + reg  [verified m89 layout]
            float* zp = zring + (rbase + aq * 4) * 80 + n * 16 + ar;
            zp[0]   = acc[0];
            zp[80]  = acc[1];
            zp[160] = acc[2];
            zp[240] = acc[3];
        }
    };

    if (wid == 0) {
        const f32x2* wp;
        wp = (const f32x2*)(W_hh0 + l  * HID);
        #pragma unroll
        for (int k = 0; k < 10; ++k) wh0p2[k] = wp[k];
        wp = (const f32x2*)(W_hh0 + g2 * HID);
        #pragma unroll
        for (int k = 0; k < 10; ++k) wh0s2[k] = wp[k];

        const int cls = (l < 50) ? (l / 5) : 0;
        const int c4  = (l < 50) ? (l % 5) : 0;
        c4off = c4 * 16;
        wfOff = (unsigned)((cls * (T_STEPS * HID) + c4 * 4) * 4);
    } else if (wid == 1) {
        const f32x2* wp;
        wp = (const f32x2*)(W_ih1 + l  * HID);
        #pragma unroll
        for (int k = 0; k < 10; ++k) wi1p2[k] = wp[k];
        wp = (const f32x2*)(W_ih1 + g2 * HID);
        #pragma unroll
        for (int k = 0; k < 10; ++k) wi1s2[k] = wp[k];
        wp = (const f32x2*)(W_hh1 + l  * HID);
        #pragma unroll
        for (int k = 0; k < 10; ++k) wh1p2[k] = wp[k];
        wp = (const f32x2*)(W_hh1 + g2 * HID);
        #pragma unroll
        for (int k = 0; k < 10; ++k) wh1s2[k] = wp[k];
        b1p = b1[l];
        b1s = b1[g2];
    } else {
        #pragma unroll
        for (int n = 0; n < 5; ++n) {
            #pragma unroll
            for (int s = 0; s < 2; ++s) {
                const float* wp = W_ih0 + (size_t)(n * 16 + ar) * F_IN + aq * 8 + s * 32;
                mk8(*(const float4*)wp, *(const float4*)(wp + 4),
                    bfr[n][s][0], bfr[n][s][1]);
            }
            bb5[n] = b0[n * 16 + ar];
        }
        // prologue: chunks 0,1 computed; loads for chunk 2 in flight
        loadx(0); zchunk(0);
        loadx(1); zchunk(1);
        loadx(2);
    }
    __syncthreads();

    // wave0: initial z(0) from zring (window 0, written in prologue)
    if (wid == 0) {
        zpc = zring[l];
        zsc = zring[64 + (l & 15)];
    }

    #pragma unroll 8
    for (int t = 0; t < T_STEPS + 4; ++t) {
        if (wid == 0) {
            const int sigma = t - 4;                    // FC step
            // prefetch wf for next step's FC, one full step early
            float4 wfn = make_float4(0.f, 0.f, 0.f, 0.f);
            if (t >= 3 && t < T_STEPS + 3) {
                wfn = *(const float4*)(Wfb + wfOff);
                wfOff += HID * 4;
            }
            if (t < T_STEPS) {
                const float zp = zpc, zs = zsc;
                if (t + 1 < T_STEPS) {                  // prefetch z(t+1) from LDS
                    const unsigned tn = (unsigned)(t + 1);
                    const unsigned rb = ((tn >> 4) % 3u) * 16 + (tn & 15u);
                    zpc = zring[rb * 80 + l];
                    zsc = zring[rb * 80 + 64 + (l & 15)];
                }
                // h0(t-1): 5 uniform ds_read_b128
                f32x2 h2[10];
                {
                    const f32x4* hp = (const f32x4*)(ringH0 + ((t + 3) & 3) * 24);
                    #pragma unroll
                    for (int k = 0; k < 5; ++k) {
                        const f32x4 v = hp[k];
                        h2[2 * k]     = __builtin_shufflevector(v, v, 0, 1);
                        h2[2 * k + 1] = __builtin_shufflevector(v, v, 2, 3);
                    }
                }
                f32x2 aP = {zp, 0.f}, aP1 = {0.f, 0.f};
                f32x2 aS = {zs, 0.f}, aS1 = {0.f, 0.f};
                #pragma unroll
                for (int j = 0; j < 5; ++j) {
                    aP  = pkfma(h2[j],     wh0p2[j],     aP);
                    aP1 = pkfma(h2[5 + j], wh0p2[5 + j], aP1);
                    aS  = pkfma(h2[j],     wh0s2[j],     aS);
                    aS1 = pkfma(h2[5 + j], wh0s2[5 + j], aS1);
                }
                const float a_p = (aP.x + aP1.x) + (aP.y + aP1.y);
                const float a_s = (aS.x + aS1.x) + (aS.y + aS1.y);
                const float actP = fmaf(rcpf(1.f + exp2f(a_p * mnegP)), sclP, biaP);
                const float actS = rcpf(1.f + exp2f(a_s * -1.442695041f));
                const float fv = bperm(idxF, actP), gv = bperm(idxG, actP);
                const float oA = bperm(idxO, actP), oB = bperm(idxOB, actS);
                const float ov = (l < 4) ? oA : oB;
                c0 = fmaf(fv, c0, actP * gv);
                const float h0v = ov * fmaf(rcpf(1.f + exp2f(c0 * -2.885390082f)), 2.f, -1.f);
                if (l < HID) ringH0[(t & 3) * 24 + l] = h0v;
            }
            if (sigma >= 0) {
                const float4 h1q = *(const float4*)((const char*)ringH1 +
                                                    ((sigma & 7) * 96) + c4off);
                facc2 = pkfma((f32x2){h1q.x, h1q.y}, (f32x2){wfc.x, wfc.y}, facc2);
                facc2 = pkfma((f32x2){h1q.z, h1q.w}, (f32x2){wfc.z, wfc.w}, facc2);
            }
            wfc = wfn;
        } else if (wid == 1) {
            const int tau = t - 2;                      // layer1 step
            if (tau >= 0 && tau < T_STEPS) {
                f32x2 h02[10], h12[10];
                {
                    const f32x4* hp = (const f32x4*)(ringH0 + (tau & 3) * 24);
                    const f32x4* hq = (const f32x4*)(ringH1 + ((tau + 7) & 7) * 24);
                    #pragma unroll
                    for (int k = 0; k < 5; ++k) {
                        const f32x4 v = hp[k];
                        const f32x4 u = hq[k];
                        h02[2 * k]     = __builtin_shufflevector(v, v, 0, 1);
                        h02[2 * k + 1] = __builtin_shufflevector(v, v, 2, 3);
                        h12[2 * k]     = __builtin_shufflevector(u, u, 0, 1);
                        h12[2 * k + 1] = __builtin_shufflevector(u, u, 2, 3);
                    }
                }
                f32x2 bP = {b1p, 0.f}, bP1 = {0.f, 0.f};
                f32x2 bS = {b1s, 0.f}, bS1 = {0.f, 0.f};
                #pragma unroll
                for (int j = 0; j < 5; ++j) {
                    bP  = pkfma(h12[j],     wh1p2[j],     bP);
                    bP1 = pkfma(h12[5 + j], wh1p2[5 + j], bP1);
                    bS  = pkfma(h12[j],     wh1s2[j],     bS);
                    bS1 = pkfma(h12[5 + j], wh1s2[5 + j], bS1);
                }
                #pragma unroll
                for (int j = 0; j < 5; ++j) {
                    bP  = pkfma(h02[j],     wi1p2[j],     bP);
                    bP1 = pkfma(h02[5 + j], wi1p2[5 + j], bP1);
                    bS  = pkfma(h02[j],     wi1s2[j],     bS);
                    bS1 = pkfma(h02[5 + j], wi1s2[5 + j], bS1);
                }
                const float b_p = (bP.x + bP1.x) + (bP.y + bP1.y);
                const float b_s = (bS.x + bS1.x) + (bS.y + bS1.y);
                const float actQ = fmaf(rcpf(1.f + exp2f(b_p * mnegP)), sclP, biaP);
                const float actT = rcpf(1.f + exp2f(b_s * -1.442695041f));
                const float fv = bperm(idxF, actQ), gv = bperm(idxG, actQ);
                const float oA = bperm(idxO, actQ), oB = bperm(idxOB, actT);
                const float ov = (l < 4) ? oA : oB;
                c1 = fmaf(fv, c1, actQ * gv);
                const float h1v = ov * fmaf(rcpf(1.f + exp2f(c1 * -2.885390082f)), 2.f, -1.f);
                if (l < HID) ringH1[(tau & 7) * 24 + l] = h1v;
            }
        } else {
            // wave2: at each window start, materialize chunk (t/16 + 2) from the
            // prefetched regs, then issue loads for the next chunk.
            if ((t & 15) == 0) {
                const int c = (t >> 4) + 2;
                if (c < 32) {
                    zchunk(c);
                    if (c + 1 < 32) loadx(c + 1);
                }
            }
        }
        if (t & 1) {
            // LDS-only drain + raw barrier (global prefetches stay in flight)
            asm volatile("s_waitcnt lgkmcnt(0)" ::: "memory");
            __builtin_amdgcn_s_barrier();
            asm volatile("" ::: "memory");
        }
    }

    // ---- epilogue: wave0 reduces FC partials (5 chunk lanes per class) ----
    if (wid == 0) {
        const float f = facc2.x + facc2.y;
        float r = f;
        r += __shfl(f, l + 1);
        r += __shfl(f, l + 2);
        r += __shfl(f, l + 3);
        r += __shfl(f, l + 4);
        if (l < 50 && (l % 5) == 0)
            out[(size_t)b * NCLS + (l / 5)] = r + b_fc[l / 5];
    }
}

extern "C" void kernel_launch(void* const* d_in, const int* in_sizes, int n_in,
                              void* d_out, int out_size, void* d_ws, size_t ws_size,
                              hipStream_t stream) {
    const float* x     = (const float*)d_in[0];
    const float* W_ih0 = (const float*)d_in[1];
    const float* W_hh0 = (const float*)d_in[2];
    const float* b0    = (const float*)d_in[3];
    const float* W_ih1 = (const float*)d_in[4];
    const float* W_hh1 = (const float*)d_in[5];
    const float* b1    = (const float*)d_in[6];
    const float* W_fc  = (const float*)d_in[7];
    const float* b_fc  = (const float*)d_in[8];
    float* out = (float*)d_out;

    lstm_fused<<<dim3(BATCH), dim3(192), 0, stream>>>(
        x, W_ih0, W_hh0, b0, W_ih1, W_hh1, b1, W_fc, b_fc, out);
}